// Round 1
// baseline (346.040 us; speedup 1.0000x reference)
//
#include <hip/hip_runtime.h>
#include <hip/hip_bf16.h>

// Problem constants (B,S,H,D_LLM)=(16,4096,1024,4096), MEM_EVERY=64
#define Bn 16
#define Sn 4096
#define Hn 1024
#define Dn 4096
#define Mn 64            // S / MEM_EVERY
#define LN_EPS 1e-5f

typedef float f32x4 __attribute__((ext_vector_type(4)));
typedef short bf16x8 __attribute__((ext_vector_type(8)));

// round-to-nearest-even f32 -> bf16 bits (inputs are finite; no NaN path needed)
__device__ __forceinline__ unsigned short f2bf(float f) {
    union { float f; unsigned u; } in; in.f = f;
    unsigned u = in.u;
    return (unsigned short)((u + 0x7fffu + ((u >> 16) & 1u)) >> 16);
}

// ---------------------------------------------------------------------------
// Kernel 1: per-batch scan of input_ids -> ordered list of mem-token positions
// pos[b*Mn + m] = s-index of the (m+1)-th masked token, or -1 if absent.
// ---------------------------------------------------------------------------
__global__ void scan_pos(const int* __restrict__ ids,
                         const int* __restrict__ memid_p,
                         int* __restrict__ pos) {
    const int b = blockIdx.x;
    const int t = threadIdx.x;           // 256 threads
    const int memid = *memid_p;
    __shared__ int counts[256];
    __shared__ int offs[256];

    // init (ws is poisoned 0xAA every call)
    for (int m = t; m < Mn; m += 256) pos[b * Mn + m] = -1;

    const int CH = Sn / 256;             // 16 ids per thread
    const int* row = ids + (size_t)b * Sn;
    int local[CH];
    int cnt = 0;
    #pragma unroll
    for (int i = 0; i < CH; ++i) {
        int s = t * CH + i;
        if (row[s] == memid) local[cnt++] = s;
    }
    counts[t] = cnt;
    __syncthreads();
    if (t == 0) {
        int acc = 0;
        for (int i = 0; i < 256; ++i) { offs[i] = acc; acc += counts[i]; }
    }
    __syncthreads();
    int base = offs[t];
    for (int i = 0; i < cnt; ++i) {
        int m = base + i;
        if (m < Mn) pos[b * Mn + m] = local[i];   // extras dropped (matches scatter OOB drop)
    }
}

// ---------------------------------------------------------------------------
// Kernel 2: gather masked rows, LayerNorm, write bf16 A[r][h]  (r = b*Mn+m)
// One block (256 thr) per row; each thread handles 4 consecutive floats.
// ---------------------------------------------------------------------------
__global__ void ln_gather(const float* __restrict__ hidden,
                          const float* __restrict__ gamma,
                          const float* __restrict__ beta,
                          const int* __restrict__ pos,
                          unsigned short* __restrict__ A) {
    const int r = blockIdx.x;            // 0..Bn*Mn-1
    const int b = r / Mn;
    const int t = threadIdx.x;           // 256
    unsigned short* arow = A + (size_t)r * Hn;
    const int s = pos[r];
    if (s < 0) {                          // missing mem token -> zero row (ref: buf stays 0)
        ushort4 z = make_ushort4(0, 0, 0, 0);
        ((ushort4*)arow)[t] = z;
        return;
    }
    const float* x = hidden + ((size_t)b * Sn + s) * Hn;
    float4 v = ((const float4*)x)[t];
    float sum = v.x + v.y + v.z + v.w;
    float sq  = v.x * v.x + v.y * v.y + v.z * v.z + v.w * v.w;
    #pragma unroll
    for (int o = 32; o >= 1; o >>= 1) {
        sum += __shfl_down(sum, o, 64);
        sq  += __shfl_down(sq,  o, 64);
    }
    __shared__ float s_sum[4], s_sq[4];
    int wave = t >> 6, lane = t & 63;
    if (lane == 0) { s_sum[wave] = sum; s_sq[wave] = sq; }
    __syncthreads();
    float tot   = s_sum[0] + s_sum[1] + s_sum[2] + s_sum[3];
    float totsq = s_sq[0]  + s_sq[1]  + s_sq[2]  + s_sq[3];
    float mu   = tot * (1.0f / Hn);
    float var  = totsq * (1.0f / Hn) - mu * mu;
    float rstd = rsqrtf(var + LN_EPS);
    float4 g  = ((const float4*)gamma)[t];
    float4 be = ((const float4*)beta)[t];
    ushort4 o16;
    o16.x = f2bf((v.x - mu) * rstd * g.x + be.x);
    o16.y = f2bf((v.y - mu) * rstd * g.y + be.y);
    o16.z = f2bf((v.z - mu) * rstd * g.z + be.z);
    o16.w = f2bf((v.w - mu) * rstd * g.w + be.w);
    ((ushort4*)arow)[t] = o16;
}

// ---------------------------------------------------------------------------
// Kernel 3: cast W (f32, [Dn][Hn] row-major) -> bf16 bits
// ---------------------------------------------------------------------------
__global__ void cast_w(const float* __restrict__ W, unsigned short* __restrict__ Wb) {
    size_t i = (size_t)blockIdx.x * blockDim.x + threadIdx.x;  // one float4 each
    float4 v = ((const float4*)W)[i];
    ushort4 o;
    o.x = f2bf(v.x); o.y = f2bf(v.y); o.z = f2bf(v.z); o.w = f2bf(v.w);
    ((ushort4*)Wb)[i] = o;
}

// ---------------------------------------------------------------------------
// Kernel 4: C[r][d] = sum_h A[r][h]*W[d][h] + bias[d]   (m97-style bf16 MFMA)
// A: [1024][1024] bf16 (K contiguous), Wb: [4096][1024] bf16 (K contiguous).
// 128x128 tile, BK=32, 256 threads (4 waves, 2x2), grid (Dn/128, rows/128).
// ---------------------------------------------------------------------------
__global__ __launch_bounds__(256) void gemm_bt(
        const unsigned short* __restrict__ A,
        const unsigned short* __restrict__ Wb,
        const float* __restrict__ bias,
        float* __restrict__ C) {
    __shared__ unsigned short As[128 * 32];   // 8 KB, row-major [row][k]
    __shared__ unsigned short Bs[128 * 32];   // 8 KB
    const int K = Hn;
    const int tid  = threadIdx.x;
    const int wave = tid >> 6;
    const int lane = tid & 63;
    const int mtile = blockIdx.y;
    const int ntile = blockIdx.x;
    const unsigned short* Abase = A  + (size_t)mtile * 128 * K;
    const unsigned short* Bbase = Wb + (size_t)ntile * 128 * K;

    // staging map: chunk (0..7) = 16 rows; lane -> row = chunk*16 + lane/4,
    // k-offset = (lane&3)*8 bf16.  LDS dest = base + chunk*1024B + lane*16B.
    const int rsub = lane >> 2;
    const int kb   = (lane & 3) * 8;
    const int wr = wave >> 1, wc = wave & 1;   // 2x2 waves, each 64x64
    const int quad = lane >> 4, l15 = lane & 15;

    f32x4 acc[4][4] = {};

    for (int k0 = 0; k0 < K; k0 += 32) {
        __syncthreads();   // prior iter's ds_reads done before overwrite
        #pragma unroll
        for (int c = 0; c < 2; ++c) {
            int chunk = wave * 2 + c;
            int row = chunk * 16 + rsub;
            const unsigned short* ga = Abase + (size_t)row * K + k0 + kb;
            const unsigned short* gb = Bbase + (size_t)row * K + k0 + kb;
            __builtin_amdgcn_global_load_lds(
                (const __attribute__((address_space(1))) void*)ga,
                (__attribute__((address_space(3))) void*)(As + chunk * 512), 16, 0, 0);
            __builtin_amdgcn_global_load_lds(
                (const __attribute__((address_space(1))) void*)gb,
                (__attribute__((address_space(3))) void*)(Bs + chunk * 512), 16, 0, 0);
        }
        __syncthreads();   // compiler inserts vmcnt(0) drain before barrier

        bf16x8 af[4], bfr[4];
        #pragma unroll
        for (int i = 0; i < 4; ++i)
            af[i] = *(const bf16x8*)(As + (wr * 64 + 16 * i + l15) * 32 + quad * 8);
        #pragma unroll
        for (int j = 0; j < 4; ++j)
            bfr[j] = *(const bf16x8*)(Bs + (wc * 64 + 16 * j + l15) * 32 + quad * 8);
        #pragma unroll
        for (int i = 0; i < 4; ++i)
            #pragma unroll
            for (int j = 0; j < 4; ++j)
                acc[i][j] = __builtin_amdgcn_mfma_f32_16x16x32_bf16(
                                af[i], bfr[j], acc[i][j], 0, 0, 0);
    }

    // epilogue: C/D layout col=lane&15, row=quad*4+reg  [verified m89/m91]
    const int crow = mtile * 128 + wr * 64;
    const int ccol = ntile * 128 + wc * 64;
    #pragma unroll
    for (int j = 0; j < 4; ++j) {
        int col = ccol + 16 * j + l15;
        float bv = bias[col];
        #pragma unroll
        for (int i = 0; i < 4; ++i) {
            int r0 = crow + 16 * i + quad * 4;
            float* cp = C + (size_t)r0 * Dn + col;
            #pragma unroll
            for (int rg = 0; rg < 4; ++rg)
                cp[(size_t)rg * Dn] = acc[i][j][rg] + bv;
        }
    }
}

extern "C" void kernel_launch(void* const* d_in, const int* in_sizes, int n_in,
                              void* d_out, int out_size, void* d_ws, size_t ws_size,
                              hipStream_t stream) {
    const float* hidden = (const float*)d_in[0];
    const float* gamma  = (const float*)d_in[1];
    const float* beta   = (const float*)d_in[2];
    const float* W      = (const float*)d_in[3];
    const float* bias   = (const float*)d_in[4];
    const int*   ids    = (const int*)d_in[5];
    const int*   memid  = (const int*)d_in[6];
    float* out = (float*)d_out;

    char* ws = (char*)d_ws;
    int* pos = (int*)ws;                                          // 4 KB
    unsigned short* Abf = (unsigned short*)(ws + 4096);           // 2 MB
    unsigned short* Wbf = (unsigned short*)(ws + 4096 + (size_t)Bn * Mn * Hn * 2); // 8 MB

    scan_pos <<<Bn, 256, 0, stream>>>(ids, memid, pos);
    ln_gather<<<Bn * Mn, 256, 0, stream>>>(hidden, gamma, beta, pos, Abf);
    cast_w   <<<(Dn * Hn / 4) / 256, 256, 0, stream>>>(W, Wbf);
    gemm_bt  <<<dim3(Dn / 128, (Bn * Mn) / 128), 256, 0, stream>>>(Abf, Wbf, bias, out);
}

// Round 2
// 342.386 us; speedup vs baseline: 1.0107x; 1.0107x over previous
//
#include <hip/hip_runtime.h>
#include <hip/hip_bf16.h>

// Problem constants (B,S,H,D_LLM)=(16,4096,1024,4096), MEM_EVERY=64
#define Bn 16
#define Sn 4096
#define Hn 1024
#define Dn 4096
#define Mn 64            // S / MEM_EVERY
#define LN_EPS 1e-5f

typedef float f32x4 __attribute__((ext_vector_type(4)));
typedef short bf16x8 __attribute__((ext_vector_type(8)));

// round-to-nearest-even f32 -> bf16 bits (inputs are finite; no NaN path needed)
__device__ __forceinline__ unsigned short f2bf(float f) {
    union { float f; unsigned u; } in; in.f = f;
    unsigned u = in.u;
    return (unsigned short)((u + 0x7fffu + ((u >> 16) & 1u)) >> 16);
}

// ---------------------------------------------------------------------------
// Kernel 1: per-batch scan of input_ids -> ordered list of mem-token positions
// pos[b*Mn + m] = s-index of the (m+1)-th masked token, or -1 if absent.
// ---------------------------------------------------------------------------
__global__ void scan_pos(const int* __restrict__ ids,
                         const int* __restrict__ memid_p,
                         int* __restrict__ pos) {
    const int b = blockIdx.x;
    const int t = threadIdx.x;           // 256 threads
    const int memid = *memid_p;
    __shared__ int counts[256];
    __shared__ int offs[256];

    for (int m = t; m < Mn; m += 256) pos[b * Mn + m] = -1;

    const int CH = Sn / 256;             // 16 ids per thread
    const int* row = ids + (size_t)b * Sn;
    int local[CH];
    int cnt = 0;
    #pragma unroll
    for (int i = 0; i < CH; ++i) {
        int s = t * CH + i;
        if (row[s] == memid) local[cnt++] = s;
    }
    counts[t] = cnt;
    __syncthreads();
    if (t == 0) {
        int acc = 0;
        for (int i = 0; i < 256; ++i) { offs[i] = acc; acc += counts[i]; }
    }
    __syncthreads();
    int base = offs[t];
    for (int i = 0; i < cnt; ++i) {
        int m = base + i;
        if (m < Mn) pos[b * Mn + m] = local[i];   // extras dropped (matches scatter OOB drop)
    }
}

// ---------------------------------------------------------------------------
// Kernel 2: gather masked rows, LayerNorm, write bf16 A[r][h]  (r = b*Mn+m)
// One block (256 thr) per row; each thread handles 4 consecutive floats.
// ---------------------------------------------------------------------------
__global__ void ln_gather(const float* __restrict__ hidden,
                          const float* __restrict__ gamma,
                          const float* __restrict__ beta,
                          const int* __restrict__ pos,
                          unsigned short* __restrict__ A) {
    const int r = blockIdx.x;            // 0..Bn*Mn-1
    const int b = r / Mn;
    const int t = threadIdx.x;           // 256
    unsigned short* arow = A + (size_t)r * Hn;
    const int s = pos[r];
    if (s < 0) {                          // missing mem token -> zero row (ref: buf stays 0)
        ushort4 z = make_ushort4(0, 0, 0, 0);
        ((ushort4*)arow)[t] = z;
        return;
    }
    const float* x = hidden + ((size_t)b * Sn + s) * Hn;
    float4 v = ((const float4*)x)[t];
    float sum = v.x + v.y + v.z + v.w;
    float sq  = v.x * v.x + v.y * v.y + v.z * v.z + v.w * v.w;
    #pragma unroll
    for (int o = 32; o >= 1; o >>= 1) {
        sum += __shfl_down(sum, o, 64);
        sq  += __shfl_down(sq,  o, 64);
    }
    __shared__ float s_sum[4], s_sq[4];
    int wave = t >> 6, lane = t & 63;
    if (lane == 0) { s_sum[wave] = sum; s_sq[wave] = sq; }
    __syncthreads();
    float tot   = s_sum[0] + s_sum[1] + s_sum[2] + s_sum[3];
    float totsq = s_sq[0]  + s_sq[1]  + s_sq[2]  + s_sq[3];
    float mu   = tot * (1.0f / Hn);
    float var  = totsq * (1.0f / Hn) - mu * mu;
    float rstd = rsqrtf(var + LN_EPS);
    float4 g  = ((const float4*)gamma)[t];
    float4 be = ((const float4*)beta)[t];
    ushort4 o16;
    o16.x = f2bf((v.x - mu) * rstd * g.x + be.x);
    o16.y = f2bf((v.y - mu) * rstd * g.y + be.y);
    o16.z = f2bf((v.z - mu) * rstd * g.z + be.z);
    o16.w = f2bf((v.w - mu) * rstd * g.w + be.w);
    ((ushort4*)arow)[t] = o16;
}

// ---------------------------------------------------------------------------
// Kernel 3: cast W (f32, [Dn][Hn] row-major) -> bf16 bits
// ---------------------------------------------------------------------------
__global__ void cast_w(const float* __restrict__ W, unsigned short* __restrict__ Wb) {
    size_t i = (size_t)blockIdx.x * blockDim.x + threadIdx.x;  // one float4 each
    float4 v = ((const float4*)W)[i];
    ushort4 o;
    o.x = f2bf(v.x); o.y = f2bf(v.y); o.z = f2bf(v.z); o.w = f2bf(v.w);
    ((ushort4*)Wb)[i] = o;
}

// ---------------------------------------------------------------------------
// Kernel 4: C[r][d] = sum_h A[r][h]*W[d][h] + bias[d]   (bf16 MFMA, m97-style)
// 64(rows) x 128(cols) tile, BK=32, 256 threads = 4 waves side-by-side in N.
// Grid (Dn/128, rows/64) = (32,16) = 512 blocks -> 2 blocks/CU (8 waves/CU)
// for cross-block latency overlap (R1 ran 1 block/CU and was latency-bound).
// ---------------------------------------------------------------------------
__global__ __launch_bounds__(256) void gemm_bt(
        const unsigned short* __restrict__ A,
        const unsigned short* __restrict__ Wb,
        const float* __restrict__ bias,
        float* __restrict__ C) {
    __shared__ unsigned short As[64 * 32];    // 4 KB, row-major [row][k]
    __shared__ unsigned short Bs[128 * 32];   // 8 KB
    const int K = Hn;
    const int tid  = threadIdx.x;
    const int wave = tid >> 6;               // 0..3, owns cols [wave*32, wave*32+32)
    const int lane = tid & 63;
    const int mtile = blockIdx.y;
    const int ntile = blockIdx.x;
    const unsigned short* Abase = A  + (size_t)mtile * 64 * K;
    const unsigned short* Bbase = Wb + (size_t)ntile * 128 * K;

    // staging map: chunk = 16 rows x 32 k = 1 KB; lane -> row = chunk*16+lane/4,
    // k-off = (lane&3)*8 bf16. LDS dest = base + chunk*1024B (+lane*16B implicit).
    const int rsub = lane >> 2;
    const int kb   = (lane & 3) * 8;
    const int quad = lane >> 4, l15 = lane & 15;

    f32x4 acc[4][2] = {};

    for (int k0 = 0; k0 < K; k0 += 32) {
        __syncthreads();   // prior iter's ds_reads done before overwrite
        {   // A: 4 chunks total, one per wave
            int row = wave * 16 + rsub;
            const unsigned short* ga = Abase + (size_t)row * K + k0 + kb;
            __builtin_amdgcn_global_load_lds(
                (const __attribute__((address_space(1))) void*)ga,
                (__attribute__((address_space(3))) void*)(As + wave * 512), 16, 0, 0);
        }
        #pragma unroll
        for (int c = 0; c < 2; ++c) {   // B: 8 chunks, two per wave
            int chunk = wave * 2 + c;
            int row = chunk * 16 + rsub;
            const unsigned short* gb = Bbase + (size_t)row * K + k0 + kb;
            __builtin_amdgcn_global_load_lds(
                (const __attribute__((address_space(1))) void*)gb,
                (__attribute__((address_space(3))) void*)(Bs + chunk * 512), 16, 0, 0);
        }
        __syncthreads();   // vmcnt(0) drain inserted by compiler before barrier

        bf16x8 af[4], bfr[2];
        #pragma unroll
        for (int i = 0; i < 4; ++i)
            af[i] = *(const bf16x8*)(As + (16 * i + l15) * 32 + quad * 8);
        #pragma unroll
        for (int j = 0; j < 2; ++j)
            bfr[j] = *(const bf16x8*)(Bs + (wave * 32 + 16 * j + l15) * 32 + quad * 8);
        #pragma unroll
        for (int i = 0; i < 4; ++i)
            #pragma unroll
            for (int j = 0; j < 2; ++j)
                acc[i][j] = __builtin_amdgcn_mfma_f32_16x16x32_bf16(
                                af[i], bfr[j], acc[i][j], 0, 0, 0);
    }

    // epilogue: C/D layout col=lane&15, row=quad*4+reg  [verified m89/m91]
    const int crow = mtile * 64;
    const int ccol = ntile * 128 + wave * 32;
    #pragma unroll
    for (int j = 0; j < 2; ++j) {
        int col = ccol + 16 * j + l15;
        float bv = bias[col];
        #pragma unroll
        for (int i = 0; i < 4; ++i) {
            int r0 = crow + 16 * i + quad * 4;
            float* cp = C + (size_t)r0 * Dn + col;
            #pragma unroll
            for (int rg = 0; rg < 4; ++rg)
                cp[(size_t)rg * Dn] = acc[i][j][rg] + bv;
        }
    }
}

extern "C" void kernel_launch(void* const* d_in, const int* in_sizes, int n_in,
                              void* d_out, int out_size, void* d_ws, size_t ws_size,
                              hipStream_t stream) {
    const float* hidden = (const float*)d_in[0];
    const float* gamma  = (const float*)d_in[1];
    const float* beta   = (const float*)d_in[2];
    const float* W      = (const float*)d_in[3];
    const float* bias   = (const float*)d_in[4];
    const int*   ids    = (const int*)d_in[5];
    const int*   memid  = (const int*)d_in[6];
    float* out = (float*)d_out;

    char* ws = (char*)d_ws;
    int* pos = (int*)ws;                                          // 4 KB
    unsigned short* Abf = (unsigned short*)(ws + 4096);           // 2 MB
    unsigned short* Wbf = (unsigned short*)(ws + 4096 + (size_t)Bn * Mn * Hn * 2); // 8 MB

    scan_pos <<<Bn, 256, 0, stream>>>(ids, memid, pos);
    ln_gather<<<Bn * Mn, 256, 0, stream>>>(hidden, gamma, beta, pos, Abf);
    cast_w   <<<(Dn * Hn / 4) / 256, 256, 0, stream>>>(W, Wbf);
    gemm_bt  <<<dim3(Dn / 128, (Bn * Mn) / 64), 256, 0, stream>>>(Abf, Wbf, bias, out);
}

// Round 3
// 335.189 us; speedup vs baseline: 1.0324x; 1.0215x over previous
//
#include <hip/hip_runtime.h>
#include <hip/hip_bf16.h>

// Problem constants (B,S,H,D_LLM)=(16,4096,1024,4096), MEM_EVERY=64
#define Bn 16
#define Sn 4096
#define Hn 1024
#define Dn 4096
#define Mn 64            // S / MEM_EVERY
#define LN_EPS 1e-5f

typedef float f32x4 __attribute__((ext_vector_type(4)));
typedef short bf16x8 __attribute__((ext_vector_type(8)));

// round-to-nearest-even f32 -> bf16 bits (inputs are finite; no NaN path needed)
__device__ __forceinline__ unsigned short f2bf(float f) {
    union { float f; unsigned u; } in; in.f = f;
    unsigned u = in.u;
    return (unsigned short)((u + 0x7fffu + ((u >> 16) & 1u)) >> 16);
}

// ---------------------------------------------------------------------------
// Fused prep kernel, grid = 1024 + 4096 blocks x 256 threads.
//   blocks [0,1024):    row r = blockIdx: scan ids[b] for the (r%64)-th mem
//                       token (block-local, no cross-block dep), gather that
//                       hidden row, LayerNorm, write bf16 A[r][:].
//   blocks [1024,5120): cast W f32 -> bf16 (4 floats/thread).
// Fusing removes 2 kernel launches and the scan->gather dependency stall;
// the 16 KB/block ids re-scan is L2-resident (16 MB total re-read).
// ---------------------------------------------------------------------------
__global__ __launch_bounds__(256) void prep(
        const float* __restrict__ hidden,
        const float* __restrict__ gamma,
        const float* __restrict__ beta,
        const float* __restrict__ W,
        const int* __restrict__ ids,
        const int* __restrict__ memid_p,
        unsigned short* __restrict__ A,
        unsigned short* __restrict__ Wb) {
    const int t = threadIdx.x;

    if (blockIdx.x >= (unsigned)(Bn * Mn)) {
        // ---- W cast: 4096 blocks x 256 thr x 4 floats = 4M elements ----
        size_t i = (size_t)(blockIdx.x - Bn * Mn) * 256 + t;   // float4 index
        float4 v = ((const float4*)W)[i];
        ushort4 o;
        o.x = f2bf(v.x); o.y = f2bf(v.y); o.z = f2bf(v.z); o.w = f2bf(v.w);
        ((ushort4*)Wb)[i] = o;
        return;
    }

    // ---- scan + LN-gather for row r ----
    const int r = blockIdx.x;            // 0..Bn*Mn-1
    const int b = r >> 6;                // Mn == 64
    const int m = r & 63;                // which mem token in this batch row
    const int memid = *memid_p;

    __shared__ int counts[256];
    __shared__ int offs[256];
    __shared__ int s_pos;

    const int CH = Sn / 256;             // 16 ids per thread
    const int* row = ids + (size_t)b * Sn;
    int local[CH];
    int cnt = 0;
    #pragma unroll
    for (int i = 0; i < CH; ++i) {
        int s = t * CH + i;
        if (row[s] == memid) local[cnt++] = s;
    }
    counts[t] = cnt;
    if (t == 0) s_pos = -1;
    __syncthreads();
    if (t == 0) {
        int acc = 0;
        for (int i = 0; i < 256; ++i) { offs[i] = acc; acc += counts[i]; }
    }
    __syncthreads();
    int base = offs[t];
    if (base <= m && m < base + cnt) s_pos = local[m - base];
    __syncthreads();
    const int s = s_pos;

    unsigned short* arow = A + (size_t)r * Hn;
    if (s < 0) {                          // fewer than m+1 mem tokens -> zero row
        ushort4 z = make_ushort4(0, 0, 0, 0);
        ((ushort4*)arow)[t] = z;
        return;
    }
    const float* x = hidden + ((size_t)b * Sn + s) * Hn;
    float4 v = ((const float4*)x)[t];
    float sum = v.x + v.y + v.z + v.w;
    float sq  = v.x * v.x + v.y * v.y + v.z * v.z + v.w * v.w;
    #pragma unroll
    for (int o = 32; o >= 1; o >>= 1) {
        sum += __shfl_down(sum, o, 64);
        sq  += __shfl_down(sq,  o, 64);
    }
    __shared__ float s_sum[4], s_sq[4];
    int wave = t >> 6, lane = t & 63;
    if (lane == 0) { s_sum[wave] = sum; s_sq[wave] = sq; }
    __syncthreads();
    float tot   = s_sum[0] + s_sum[1] + s_sum[2] + s_sum[3];
    float totsq = s_sq[0]  + s_sq[1]  + s_sq[2]  + s_sq[3];
    float mu   = tot * (1.0f / Hn);
    float var  = totsq * (1.0f / Hn) - mu * mu;
    float rstd = rsqrtf(var + LN_EPS);
    float4 g  = ((const float4*)gamma)[t];
    float4 be = ((const float4*)beta)[t];
    ushort4 o16;
    o16.x = f2bf((v.x - mu) * rstd * g.x + be.x);
    o16.y = f2bf((v.y - mu) * rstd * g.y + be.y);
    o16.z = f2bf((v.z - mu) * rstd * g.z + be.z);
    o16.w = f2bf((v.w - mu) * rstd * g.w + be.w);
    ((ushort4*)arow)[t] = o16;
}

// ---------------------------------------------------------------------------
// GEMM: C[r][d] = sum_h A[r][h]*W[d][h] + bias[d]   (bf16 MFMA, m97-style)
// 64(rows) x 128(cols) tile, BK=32, 256 threads = 4 waves side-by-side in N.
// Grid (Dn/128, rows/64) = (32,16) = 512 blocks -> 2 blocks/CU (8 waves/CU).
// Measured best of {128x128 @1/CU, 64x128 @2/CU}; ~8-10 us, near its L2
// staging-traffic floor (~192 MB @ 34.5 TB/s ~ 5.6 us) overlapped with MFMA.
// ---------------------------------------------------------------------------
__global__ __launch_bounds__(256) void gemm_bt(
        const unsigned short* __restrict__ A,
        const unsigned short* __restrict__ Wb,
        const float* __restrict__ bias,
        float* __restrict__ C) {
    __shared__ unsigned short As[64 * 32];    // 4 KB, row-major [row][k]
    __shared__ unsigned short Bs[128 * 32];   // 8 KB
    const int K = Hn;
    const int tid  = threadIdx.x;
    const int wave = tid >> 6;               // 0..3, owns cols [wave*32, wave*32+32)
    const int lane = tid & 63;
    const int mtile = blockIdx.y;
    const int ntile = blockIdx.x;
    const unsigned short* Abase = A  + (size_t)mtile * 64 * K;
    const unsigned short* Bbase = Wb + (size_t)ntile * 128 * K;

    // staging map: chunk = 16 rows x 32 k = 1 KB; lane -> row = chunk*16+lane/4,
    // k-off = (lane&3)*8 bf16. LDS dest = base + chunk*1024B (+lane*16B implicit).
    const int rsub = lane >> 2;
    const int kb   = (lane & 3) * 8;
    const int quad = lane >> 4, l15 = lane & 15;

    f32x4 acc[4][2] = {};

    for (int k0 = 0; k0 < K; k0 += 32) {
        __syncthreads();   // prior iter's ds_reads done before overwrite
        {   // A: 4 chunks total, one per wave
            int row = wave * 16 + rsub;
            const unsigned short* ga = Abase + (size_t)row * K + k0 + kb;
            __builtin_amdgcn_global_load_lds(
                (const __attribute__((address_space(1))) void*)ga,
                (__attribute__((address_space(3))) void*)(As + wave * 512), 16, 0, 0);
        }
        #pragma unroll
        for (int c = 0; c < 2; ++c) {   // B: 8 chunks, two per wave
            int chunk = wave * 2 + c;
            int row = chunk * 16 + rsub;
            const unsigned short* gb = Bbase + (size_t)row * K + k0 + kb;
            __builtin_amdgcn_global_load_lds(
                (const __attribute__((address_space(1))) void*)gb,
                (__attribute__((address_space(3))) void*)(Bs + chunk * 512), 16, 0, 0);
        }
        __syncthreads();   // vmcnt(0) drain inserted by compiler before barrier

        bf16x8 af[4], bfr[2];
        #pragma unroll
        for (int i = 0; i < 4; ++i)
            af[i] = *(const bf16x8*)(As + (16 * i + l15) * 32 + quad * 8);
        #pragma unroll
        for (int j = 0; j < 2; ++j)
            bfr[j] = *(const bf16x8*)(Bs + (wave * 32 + 16 * j + l15) * 32 + quad * 8);
        #pragma unroll
        for (int i = 0; i < 4; ++i)
            #pragma unroll
            for (int j = 0; j < 2; ++j)
                acc[i][j] = __builtin_amdgcn_mfma_f32_16x16x32_bf16(
                                af[i], bfr[j], acc[i][j], 0, 0, 0);
    }

    // epilogue: C/D layout col=lane&15, row=quad*4+reg  [verified m89/m91]
    const int crow = mtile * 64;
    const int ccol = ntile * 128 + wave * 32;
    #pragma unroll
    for (int j = 0; j < 2; ++j) {
        int col = ccol + 16 * j + l15;
        float bv = bias[col];
        #pragma unroll
        for (int i = 0; i < 4; ++i) {
            int r0 = crow + 16 * i + quad * 4;
            float* cp = C + (size_t)r0 * Dn + col;
            #pragma unroll
            for (int rg = 0; rg < 4; ++rg)
                cp[(size_t)rg * Dn] = acc[i][j][rg] + bv;
        }
    }
}

extern "C" void kernel_launch(void* const* d_in, const int* in_sizes, int n_in,
                              void* d_out, int out_size, void* d_ws, size_t ws_size,
                              hipStream_t stream) {
    const float* hidden = (const float*)d_in[0];
    const float* gamma  = (const float*)d_in[1];
    const float* beta   = (const float*)d_in[2];
    const float* W      = (const float*)d_in[3];
    const float* bias   = (const float*)d_in[4];
    const int*   ids    = (const int*)d_in[5];
    const int*   memid  = (const int*)d_in[6];
    float* out = (float*)d_out;

    char* ws = (char*)d_ws;
    unsigned short* Abf = (unsigned short*)ws;                               // 2 MB
    unsigned short* Wbf = (unsigned short*)(ws + (size_t)Bn * Mn * Hn * 2);  // 8 MB

    prep   <<<Bn * Mn + Dn * Hn / 1024, 256, 0, stream>>>(hidden, gamma, beta, W,
                                                          ids, memid, Abf, Wbf);
    gemm_bt<<<dim3(Dn / 128, (Bn * Mn) / 64), 256, 0, stream>>>(Abf, Wbf, bias, out);
}